// Round 6
// baseline (308.769 us; speedup 1.0000x reference)
//
#include <hip/hip_runtime.h>
#include <math.h>

typedef __bf16 bf16_t;
typedef bf16_t bf16x8 __attribute__((ext_vector_type(8)));
typedef bf16_t bf16x4 __attribute__((ext_vector_type(4)));
typedef float  floatx4 __attribute__((ext_vector_type(4)));
typedef unsigned int u32;

#define MFMA_BF16(a, b, c) __builtin_amdgcn_mfma_f32_16x16x32_bf16((a), (b), (c), 0, 0, 0)

static constexpr int DMODEL = 1024;
static constexpr int NHEAD  = 16;
static constexpr int HDIM   = 64;
static constexpr int NBATCH = 4;
static constexpr int SEQLEN = 1024;
static constexpr int NTOK   = NBATCH * SEQLEN;  // 4096

typedef __attribute__((address_space(3))) void       as3_void;
typedef __attribute__((address_space(1))) const void as1_cvoid;

// async global->LDS: per-lane global src, LDS dest = wave-uniform base + lane*16
__device__ __forceinline__ void gload16(const void* g, void* l) {
    __builtin_amdgcn_global_load_lds((as1_cvoid*)g, (as3_void*)l, 16, 0, 0);
}

__device__ __forceinline__ bf16x8 pack_bf16x8(floatx4 lo, floatx4 hi) {
    bf16x8 r;
    r[0] = (bf16_t)lo[0]; r[1] = (bf16_t)lo[1]; r[2] = (bf16_t)lo[2]; r[3] = (bf16_t)lo[3];
    r[4] = (bf16_t)hi[0]; r[5] = (bf16_t)hi[1]; r[6] = (bf16_t)hi[2]; r[7] = (bf16_t)hi[3];
    return r;
}

// ---------------- weight transpose+convert: Wt[n][k] = bf16(W[k][n]), 4 mats ----------------
__global__ __launch_bounds__(256) void transpose_w(
    const float* __restrict__ W0, const float* __restrict__ W1,
    const float* __restrict__ W2, const float* __restrict__ W3,
    bf16_t* __restrict__ out)
{
    __shared__ float tile[32][33];
    const float* W = (blockIdx.z == 0) ? W0 : (blockIdx.z == 1) ? W1
                   : (blockIdx.z == 2) ? W2 : W3;
    bf16_t* O = out + (size_t)blockIdx.z * DMODEL * DMODEL;
    int tx = threadIdx.x, ty = threadIdx.y;           // 32 x 8
    int r0 = blockIdx.x * 32, c0 = blockIdx.y * 32;
#pragma unroll
    for (int i = 0; i < 32; i += 8)
        tile[ty + i][tx] = W[(size_t)(r0 + ty + i) * DMODEL + c0 + tx];
    __syncthreads();
#pragma unroll
    for (int i = 0; i < 32; i += 8)
        O[(size_t)(c0 + ty + i) * DMODEL + r0 + tx] = (bf16_t)tile[tx][ty + i];
}

// ---------------- QKV projection GEMM: fp32 A staged to LDS, cvt on read ----------------
// 128x128 tile, BK=32. LDS tiles are FRAGMENT-MAJOR ([kgroup][row] in 16B words) so
// ds_read_b128 lanes touch consecutive words -> bank = (row%8)*4, 2 lanes/bank = free.
// A is fp32 (8 kgroups of 4 floats); B is bf16 Wt (4 kgroups of 8 bf16).
// mode 0: Q -> [B,H,S,Dk] *1/8;  1: K -> [B,H,S,Dk];  2: V -> [B,H,Dk,S].
__global__ __launch_bounds__(256) void gemm_qkv(
    const float* __restrict__ qin, const float* __restrict__ kin, const float* __restrict__ vin,
    const bf16_t* __restrict__ Wt,
    const float* __restrict__ bq, const float* __restrict__ bk, const float* __restrict__ bv,
    bf16_t* __restrict__ Qh, bf16_t* __restrict__ Kh, bf16_t* __restrict__ Vt)
{
    const int mode = blockIdx.z;
    const float* A    = (mode == 0) ? qin : (mode == 1) ? kin : vin;
    const bf16_t* B   = Wt + (size_t)mode * DMODEL * DMODEL;
    const float* bias = (mode == 0) ? bq : (mode == 1) ? bk : bv;
    bf16_t* out       = (mode == 0) ? Qh : (mode == 1) ? Kh : Vt;

    __shared__ __align__(16) float  lAf[128 * 32];   // 16KB: word(16B) idx = g*128+row, g=0..7
    __shared__ __align__(16) bf16_t lB [128 * 32];   // 8KB:  word idx = g*128+row, g=0..3

    const int wave = threadIdx.x >> 6, lane = threadIdx.x & 63;
    const int quad = lane >> 4, l15 = lane & 15;
    const int wm = wave >> 1, wn = wave & 1;
    const int row0 = blockIdx.x * 128, col0 = blockIdx.y * 128;

    const floatx4 zero = {0.f, 0.f, 0.f, 0.f};
    floatx4 acc[4][4];
#pragma unroll
    for (int mt = 0; mt < 4; mt++)
#pragma unroll
        for (int nt = 0; nt < 4; nt++) acc[mt][nt] = zero;

    for (int k0 = 0; k0 < DMODEL; k0 += 32) {
        // A: 16 segs (4/wave); seg s=wave*4+j -> g=wave*2+(j>>1), row=(j&1)*64+lane
#pragma unroll
        for (int j = 0; j < 4; j++) {
            const int s = wave * 4 + j;
            const int g = wave * 2 + (j >> 1);
            const int r = (j & 1) * 64 + lane;
            gload16(A + (size_t)(row0 + r) * DMODEL + k0 + g * 4, lAf + s * 256);
        }
        // B: 8 segs (2/wave); seg s=wave*2+j -> g=wave, row=j*64+lane
#pragma unroll
        for (int j = 0; j < 2; j++) {
            const int s = wave * 2 + j;
            const int r = j * 64 + lane;
            gload16(B + (size_t)(col0 + r) * DMODEL + k0 + wave * 8, lB + s * 512);
        }
        __syncthreads();
        bf16x8 aF[4], bF[4];
#pragma unroll
        for (int t = 0; t < 4; t++) {
            const int ra = wm * 64 + t * 16 + l15;
            floatx4 lo = *(const floatx4*)(lAf + ((2 * quad) * 128 + ra) * 4);
            floatx4 hi = *(const floatx4*)(lAf + ((2 * quad + 1) * 128 + ra) * 4);
            aF[t] = pack_bf16x8(lo, hi);
            const int rb = wn * 64 + t * 16 + l15;
            bF[t] = *(const bf16x8*)(lB + (quad * 128 + rb) * 8);
        }
#pragma unroll
        for (int mt = 0; mt < 4; mt++)
#pragma unroll
            for (int nt = 0; nt < 4; nt++)
                acc[mt][nt] = MFMA_BF16(aF[mt], bF[nt], acc[mt][nt]);
        __syncthreads();
    }

#pragma unroll
    for (int nt = 0; nt < 4; nt++) {
        const int gn = col0 + wn * 64 + nt * 16 + l15;
        const float bb = bias[gn];
        const int hh = gn >> 6, dd = gn & 63;
#pragma unroll
        for (int mt = 0; mt < 4; mt++) {
#pragma unroll
            for (int r = 0; r < 4; r++) {
                const int tok = row0 + wm * 64 + mt * 16 + quad * 4 + r;
                const int b = tok >> 10, s = tok & 1023;
                float vv = acc[mt][nt][r] + bb;
                size_t addr;
                if (mode == 2) {
                    addr = ((size_t)((b * NHEAD + hh) * HDIM + dd)) * SEQLEN + s;
                } else {
                    if (mode == 0) vv *= 0.125f;  // 1/sqrt(Dk), exact pow2
                    addr = ((size_t)((b * NHEAD + hh) * SEQLEN + s)) * HDIM + dd;
                }
                out[addr] = (bf16_t)vv;
            }
        }
    }
}

// ---------------- output projection GEMM, 64x128 tile, fragment-major LDS ----------------
__global__ __launch_bounds__(256) void gemm_o(
    const bf16_t* __restrict__ Xa, const bf16_t* __restrict__ Wt,
    const float* __restrict__ bias, float* __restrict__ out)
{
    __shared__ __align__(16) bf16_t lA[64 * 32];     // word idx = g*64+row, g=0..3
    __shared__ __align__(16) bf16_t lB[128 * 32];    // word idx = g*128+row, g=0..3

    const int wave = threadIdx.x >> 6, lane = threadIdx.x & 63;
    const int quad = lane >> 4, l15 = lane & 15;
    const int wm = wave & 1, wn = wave >> 1;
    const int row0 = blockIdx.x * 64, col0 = blockIdx.y * 128;

    const floatx4 zero = {0.f, 0.f, 0.f, 0.f};
    floatx4 acc[2][4];
#pragma unroll
    for (int mt = 0; mt < 2; mt++)
#pragma unroll
        for (int nt = 0; nt < 4; nt++) acc[mt][nt] = zero;

    for (int k0 = 0; k0 < DMODEL; k0 += 32) {
        // A: 4 segs (1/wave): g=wave, row=lane
        gload16(Xa + (size_t)(row0 + lane) * DMODEL + k0 + wave * 8, lA + wave * 512);
        // B: 8 segs (2/wave): g=wave, row=j*64+lane
#pragma unroll
        for (int j = 0; j < 2; j++) {
            const int s = wave * 2 + j;
            const int r = j * 64 + lane;
            gload16(Wt + (size_t)(col0 + r) * DMODEL + k0 + wave * 8, lB + s * 512);
        }
        __syncthreads();
        bf16x8 aF[2], bF[4];
#pragma unroll
        for (int t = 0; t < 2; t++) {
            const int ra = wm * 32 + t * 16 + l15;
            aF[t] = *(const bf16x8*)(lA + (quad * 64 + ra) * 8);
        }
#pragma unroll
        for (int t = 0; t < 4; t++) {
            const int rb = wn * 64 + t * 16 + l15;
            bF[t] = *(const bf16x8*)(lB + (quad * 128 + rb) * 8);
        }
#pragma unroll
        for (int mt = 0; mt < 2; mt++)
#pragma unroll
            for (int nt = 0; nt < 4; nt++)
                acc[mt][nt] = MFMA_BF16(aF[mt], bF[nt], acc[mt][nt]);
        __syncthreads();
    }

#pragma unroll
    for (int nt = 0; nt < 4; nt++) {
        const int gn = col0 + wn * 64 + nt * 16 + l15;
        const float bb = bias[gn];
#pragma unroll
        for (int mt = 0; mt < 2; mt++) {
#pragma unroll
            for (int r = 0; r < 4; r++) {
                const int tok = row0 + wm * 32 + mt * 16 + quad * 4 + r;
                out[(size_t)tok * DMODEL + gn] = acc[mt][nt][r] + bb;
            }
        }
    }
}

// ---------------- causal flash attention: dual-stream, pair-balanced, no LDS ----------------
__global__ __launch_bounds__(256) void attn(
    const bf16_t* __restrict__ Qh, const bf16_t* __restrict__ Kh,
    const bf16_t* __restrict__ Vt, bf16_t* __restrict__ X)
{
    const int wave = threadIdx.x >> 6, lane = threadIdx.x & 63;
    const int quad = lane >> 4, l15 = lane & 15;
    const int L = blockIdx.x;                          // [0,512)
    const int bh = (L & 7) * 8 + ((L >> 3) & 7);       // same 8 heads stay on one XCD
    const int pb = L >> 6;                             // [0,8)
    const int t  = pb * 4 + wave;                      // pair index [0,32)
    const int b = bh >> 4, h = bh & 15;

    const int qbaseA = 16 * t, qbaseB = 1008 - 16 * t;
    const int qrowA = qbaseA + l15, qrowB = qbaseB + l15;
    const int nkA = t / 2 + 1, nkB = 32 - t / 2;

    const bf16_t* Qp = Qh + (size_t)bh * SEQLEN * HDIM;
    const bf16_t* Kp = Kh + (size_t)bh * SEQLEN * HDIM;
    const bf16_t* Vp = Vt + (size_t)bh * HDIM * SEQLEN;

    bf16x8 bQA[2], bQB[2];
#pragma unroll
    for (int c = 0; c < 2; c++) {
        bQA[c] = *(const bf16x8*)(Qp + (size_t)qrowA * HDIM + c * 32 + quad * 8);
        bQB[c] = *(const bf16x8*)(Qp + (size_t)qrowB * HDIM + c * 32 + quad * 8);
    }

    const floatx4 zero = {0.f, 0.f, 0.f, 0.f};
    float mA = -INFINITY, lA_ = 0.f, mB = -INFINITY, lB_ = 0.f;
    floatx4 oA[4], oB[4];
#pragma unroll
    for (int dt = 0; dt < 4; dt++) { oA[dt] = zero; oB[dt] = zero; }

    const int srcA = ((quad & 1) ? 32 : 0) + l15;
    const int srcB = srcA + 16;
    const bool hiP = (quad >= 2);

    for (int kc = 0; kc < nkB; kc++) {
        const int kb = kc * 32;
        bf16x8 aK0[2], aK1[2], aV[4];
#pragma unroll
        for (int c = 0; c < 2; c++) {
            aK0[c] = *(const bf16x8*)(Kp + (size_t)(kb + l15) * HDIM + c * 32 + quad * 8);
            aK1[c] = *(const bf16x8*)(Kp + (size_t)(kb + 16 + l15) * HDIM + c * 32 + quad * 8);
        }
#pragma unroll
        for (int dt = 0; dt < 4; dt++)
            aV[dt] = *(const bf16x8*)(Vp + (size_t)(dt * 16 + l15) * SEQLEN + kb + quad * 8);

        const bool doA = (kc < nkA);

        floatx4 S0B = zero, S1B = zero, S0A = zero, S1A = zero;
#pragma unroll
        for (int c = 0; c < 2; c++) {
            S0B = MFMA_BF16(aK0[c], bQB[c], S0B);
            S1B = MFMA_BF16(aK1[c], bQB[c], S1B);
        }
        if (doA) {
#pragma unroll
            for (int c = 0; c < 2; c++) {
                S0A = MFMA_BF16(aK0[c], bQA[c], S0A);
                S1A = MFMA_BF16(aK1[c], bQA[c], S1A);
            }
        }

        {   // stream B
            float s0[4], s1[4], mx = -1e30f;
#pragma unroll
            for (int r = 0; r < 4; r++) {
                const int key0 = kb + quad * 4 + r;
                s0[r] = (key0 <= qrowB)      ? S0B[r] : -1e30f;
                s1[r] = (key0 + 16 <= qrowB) ? S1B[r] : -1e30f;
                mx = fmaxf(mx, fmaxf(s0[r], s1[r]));
            }
            mx = fmaxf(mx, __shfl_xor(mx, 16));
            mx = fmaxf(mx, __shfl_xor(mx, 32));
            const float mn = fmaxf(mB, mx);
            const float alpha = __expf(mB - mn);
            mB = mn;
            float ps = 0.f;
            union { bf16_t hh2[8]; u32 u[4]; } pk;
#pragma unroll
            for (int r = 0; r < 4; r++) {
                float e0 = __expf(s0[r] - mn), e1 = __expf(s1[r] - mn);
                ps += e0 + e1;
                pk.hh2[r] = (bf16_t)e0; pk.hh2[4 + r] = (bf16_t)e1;
            }
            ps += __shfl_xor(ps, 16);
            ps += __shfl_xor(ps, 32);
            lB_ = lB_ * alpha + ps;
#pragma unroll
            for (int dt = 0; dt < 4; dt++)
#pragma unroll
                for (int r = 0; r < 4; r++) oB[dt][r] *= alpha;
            u32 a0 = __shfl(pk.u[0], srcA), a1 = __shfl(pk.u[1], srcA);
            u32 a2 = __shfl(pk.u[0], srcB), a3 = __shfl(pk.u[1], srcB);
            u32 b0 = __shfl(pk.u[2], srcA), b1 = __shfl(pk.u[3], srcA);
            u32 b2 = __shfl(pk.u[2], srcB), b3 = __shfl(pk.u[3], srcB);
            union { u32 u[4]; bf16x8 v; } bP;
            bP.u[0] = hiP ? b0 : a0; bP.u[1] = hiP ? b1 : a1;
            bP.u[2] = hiP ? b2 : a2; bP.u[3] = hiP ? b3 : a3;
#pragma unroll
            for (int dt = 0; dt < 4; dt++) oB[dt] = MFMA_BF16(aV[dt], bP.v, oB[dt]);
        }

        if (doA) {  // stream A
            float s0[4], s1[4], mx = -1e30f;
#pragma unroll
            for (int r = 0; r < 4; r++) {
                const int key0 = kb + quad * 4 + r;
                s0[r] = (key0 <= qrowA)      ? S0A[r] : -1e30f;
                s1[r] = (key0 + 16 <= qrowA) ? S1A[r] : -1e30f;
                mx = fmaxf(mx, fmaxf(s0[r], s1[r]));
            }
            mx = fmaxf(mx, __shfl_xor(mx, 16));
            mx = fmaxf(mx, __shfl_xor(mx, 32));
            const float mn = fmaxf(mA, mx);
            const float alpha = __expf(mA - mn);
            mA = mn;
            float ps = 0.f;
            union { bf16_t hh2[8]; u32 u[4]; } pk;
#pragma unroll
            for (int r = 0; r < 4; r++) {
                float e0 = __expf(s0[r] - mn), e1 = __expf(s1[r] - mn);
                ps += e0 + e1;
                pk.hh2[r] = (bf16_t)e0; pk.hh2[4 + r] = (bf16_t)e1;
            }
            ps += __shfl_xor(ps, 16);
            ps += __shfl_xor(ps, 32);
            lA_ = lA_ * alpha + ps;
#pragma unroll
            for (int dt = 0; dt < 4; dt++)
#pragma unroll
                for (int r = 0; r < 4; r++) oA[dt][r] *= alpha;
            u32 a0 = __shfl(pk.u[0], srcA), a1 = __shfl(pk.u[1], srcA);
            u32 a2 = __shfl(pk.u[0], srcB), a3 = __shfl(pk.u[1], srcB);
            u32 b0 = __shfl(pk.u[2], srcA), b1 = __shfl(pk.u[3], srcA);
            u32 b2 = __shfl(pk.u[2], srcB), b3 = __shfl(pk.u[3], srcB);
            union { u32 u[4]; bf16x8 v; } bP;
            bP.u[0] = hiP ? b0 : a0; bP.u[1] = hiP ? b1 : a1;
            bP.u[2] = hiP ? b2 : a2; bP.u[3] = hiP ? b3 : a3;
#pragma unroll
            for (int dt = 0; dt < 4; dt++) oA[dt] = MFMA_BF16(aV[dt], bP.v, oA[dt]);
        }
    }

    const float invA = 1.f / lA_, invB = 1.f / lB_;
#pragma unroll
    for (int dt = 0; dt < 4; dt++) {
        bf16x4 va, vb;
#pragma unroll
        for (int r = 0; r < 4; r++) {
            va[r] = (bf16_t)(oA[dt][r] * invA);
            vb[r] = (bf16_t)(oB[dt][r] * invB);
        }
        const size_t cofs = (size_t)h * HDIM + dt * 16 + quad * 4;
        *(bf16x4*)(&X[((size_t)(b * SEQLEN + qrowA)) * DMODEL + cofs]) = va;
        *(bf16x4*)(&X[((size_t)(b * SEQLEN + qrowB)) * DMODEL + cofs]) = vb;
    }
}

extern "C" void kernel_launch(void* const* d_in, const int* in_sizes, int n_in,
                              void* d_out, int out_size, void* d_ws, size_t ws_size,
                              hipStream_t stream)
{
    const float* q  = (const float*)d_in[0];
    const float* k  = (const float*)d_in[1];
    const float* v  = (const float*)d_in[2];
    // d_in[3] = causal mask (deterministic tril) — applied analytically
    const float* Wq = (const float*)d_in[4];
    const float* bq = (const float*)d_in[5];
    const float* Wk = (const float*)d_in[6];
    const float* bk = (const float*)d_in[7];
    const float* Wv = (const float*)d_in[8];
    const float* bv = (const float*)d_in[9];
    const float* Wo = (const float*)d_in[10];
    const float* bo = (const float*)d_in[11];
    float* out = (float*)d_out;

    char* ws = (char*)d_ws;
    const size_t MB = 1ull << 20;
    bf16_t* Wt = (bf16_t*)ws;                              // [0,8) MB: 4 transposed bf16 weights
    bf16_t* Qh = (bf16_t*)(ws + 8 * MB);                   // [8,16)
    bf16_t* Kh = (bf16_t*)(ws + 16 * MB);                  // [16,24)
    bf16_t* Vt = (bf16_t*)(ws + 24 * MB);                  // [24,32)
    bf16_t* Xa = (bf16_t*)(ws + 32 * MB);                  // [32,40) attn output bf16

    transpose_w<<<dim3(32, 32, 4), dim3(32, 8), 0, stream>>>(Wq, Wk, Wv, Wo, Wt);
    gemm_qkv<<<dim3(32, 8, 3), dim3(256), 0, stream>>>(
        q, k, v, Wt, bq, bk, bv, Qh, Kh, Vt);
    attn<<<dim3(512), dim3(256), 0, stream>>>(Qh, Kh, Vt, Xa);
    gemm_o<<<dim3(64, 8), dim3(256), 0, stream>>>(
        Xa, Wt + 3 * (size_t)DMODEL * DMODEL, bo, out);
}

// Round 7
// 272.317 us; speedup vs baseline: 1.1339x; 1.1339x over previous
//
#include <hip/hip_runtime.h>
#include <math.h>

typedef __bf16 bf16_t;
typedef bf16_t bf16x8 __attribute__((ext_vector_type(8)));
typedef bf16_t bf16x4 __attribute__((ext_vector_type(4)));
typedef float  floatx4 __attribute__((ext_vector_type(4)));
typedef unsigned int u32;

#define MFMA_BF16(a, b, c) __builtin_amdgcn_mfma_f32_16x16x32_bf16((a), (b), (c), 0, 0, 0)

static constexpr int DMODEL = 1024;
static constexpr int NHEAD  = 16;
static constexpr int HDIM   = 64;
static constexpr int NBATCH = 4;
static constexpr int SEQLEN = 1024;
static constexpr int NTOK   = NBATCH * SEQLEN;  // 4096

typedef __attribute__((address_space(3))) void       as3_void;
typedef __attribute__((address_space(1))) const void as1_cvoid;

// async global->LDS: per-lane global src, LDS dest = wave-uniform base + lane*16
__device__ __forceinline__ void gload16(const void* g, void* l) {
    __builtin_amdgcn_global_load_lds((as1_cvoid*)g, (as3_void*)l, 16, 0, 0);
}

__device__ __forceinline__ bf16x8 pack_bf16x8(floatx4 lo, floatx4 hi) {
    bf16x8 r;
    r[0] = (bf16_t)lo[0]; r[1] = (bf16_t)lo[1]; r[2] = (bf16_t)lo[2]; r[3] = (bf16_t)lo[3];
    r[4] = (bf16_t)hi[0]; r[5] = (bf16_t)hi[1]; r[6] = (bf16_t)hi[2]; r[7] = (bf16_t)hi[3];
    return r;
}

// ---------------- weight transpose+convert: Wt[n][k] = bf16(W[k][n]), 4 mats ----------------
__global__ __launch_bounds__(256) void transpose_w(
    const float* __restrict__ W0, const float* __restrict__ W1,
    const float* __restrict__ W2, const float* __restrict__ W3,
    bf16_t* __restrict__ out)
{
    __shared__ float tile[32][33];
    const float* W = (blockIdx.z == 0) ? W0 : (blockIdx.z == 1) ? W1
                   : (blockIdx.z == 2) ? W2 : W3;
    bf16_t* O = out + (size_t)blockIdx.z * DMODEL * DMODEL;
    int tx = threadIdx.x, ty = threadIdx.y;           // 32 x 8
    int r0 = blockIdx.x * 32, c0 = blockIdx.y * 32;
#pragma unroll
    for (int i = 0; i < 32; i += 8)
        tile[ty + i][tx] = W[(size_t)(r0 + ty + i) * DMODEL + c0 + tx];
    __syncthreads();
#pragma unroll
    for (int i = 0; i < 32; i += 8)
        O[(size_t)(c0 + ty + i) * DMODEL + r0 + tx] = (bf16_t)tile[tx][ty + i];
}

// ---------------- QKV projection GEMM: fp32 A staged to LDS, cvt on read ----------------
// 128x128 tile, BK=32, row-major LDS with XOR chunk-swizzle:
//   A (fp32, 8x16B words/row): word(row,q) = row*8 + (q ^ (row&7))
//   B (bf16, 4x16B words/row): word(row,q) = row*4 + (q ^ ((row>>1)&3))
// Staging stays coalesced (lanes of one row fetch that row's chunks, permuted);
// fragment ds_read_b128 spreads over all 8 bank groups (2 lanes/bank = free).
// mode 0: Q -> [B,H,S,Dk] *1/8;  1: K -> [B,H,S,Dk];  2: V -> [B,H,Dk,S].
__global__ __launch_bounds__(256) void gemm_qkv(
    const float* __restrict__ qin, const float* __restrict__ kin, const float* __restrict__ vin,
    const bf16_t* __restrict__ Wt,
    const float* __restrict__ bq, const float* __restrict__ bk, const float* __restrict__ bv,
    bf16_t* __restrict__ Qh, bf16_t* __restrict__ Kh, bf16_t* __restrict__ Vt)
{
    const int mode = blockIdx.z;
    const float* A    = (mode == 0) ? qin : (mode == 1) ? kin : vin;
    const bf16_t* B   = Wt + (size_t)mode * DMODEL * DMODEL;
    const float* bias = (mode == 0) ? bq : (mode == 1) ? bk : bv;
    bf16_t* out       = (mode == 0) ? Qh : (mode == 1) ? Kh : Vt;

    __shared__ __align__(16) float  lAf[128 * 32];   // 16KB, 8 words/row
    __shared__ __align__(16) bf16_t lB [128 * 32];   // 8KB,  4 words/row

    const int wave = threadIdx.x >> 6, lane = threadIdx.x & 63;
    const int quad = lane >> 4, l15 = lane & 15;
    const int wm = wave >> 1, wn = wave & 1;
    const int row0 = blockIdx.x * 128, col0 = blockIdx.y * 128;

    // A staging: seg covers 8 rows x 8 chunks; lane -> row seg*8+(lane>>3), holds chunk lane&7
    const int arl = lane >> 3, ac = lane & 7;
    // B staging: seg covers 16 rows x 4 chunks
    const int brl = lane >> 2, bc = lane & 3;

    const floatx4 zero = {0.f, 0.f, 0.f, 0.f};
    floatx4 acc[4][4];
#pragma unroll
    for (int mt = 0; mt < 4; mt++)
#pragma unroll
        for (int nt = 0; nt < 4; nt++) acc[mt][nt] = zero;

    for (int k0 = 0; k0 < DMODEL; k0 += 32) {
        // A: 16 segs (4/wave)
#pragma unroll
        for (int j = 0; j < 4; j++) {
            const int s = wave * 4 + j;
            const int r = s * 8 + arl;                   // tile row; r&7 == arl
            const int q = ac ^ arl;                      // content chunk (4 floats)
            gload16(A + (size_t)(row0 + r) * DMODEL + k0 + q * 4, lAf + s * 256);
        }
        // B: 8 segs (2/wave)
#pragma unroll
        for (int j = 0; j < 2; j++) {
            const int s = wave * 2 + j;
            const int r = s * 16 + brl;
            const int q = bc ^ ((r >> 1) & 3);           // content chunk (8 bf16)
            gload16(B + (size_t)(col0 + r) * DMODEL + k0 + q * 8, lB + s * 512);
        }
        __syncthreads();
        bf16x8 aF[4], bF[4];
#pragma unroll
        for (int t = 0; t < 4; t++) {
            const int ra = wm * 64 + t * 16 + l15;
            const int wlo = ra * 8 + ((2 * quad)     ^ (ra & 7));
            const int whi = ra * 8 + ((2 * quad + 1) ^ (ra & 7));
            floatx4 lo = *(const floatx4*)(lAf + wlo * 4);
            floatx4 hi = *(const floatx4*)(lAf + whi * 4);
            aF[t] = pack_bf16x8(lo, hi);
            const int rb = wn * 64 + t * 16 + l15;
            const int wb = rb * 4 + (quad ^ ((rb >> 1) & 3));
            bF[t] = *(const bf16x8*)(lB + wb * 8);
        }
#pragma unroll
        for (int mt = 0; mt < 4; mt++)
#pragma unroll
            for (int nt = 0; nt < 4; nt++)
                acc[mt][nt] = MFMA_BF16(aF[mt], bF[nt], acc[mt][nt]);
        __syncthreads();
    }

#pragma unroll
    for (int nt = 0; nt < 4; nt++) {
        const int gn = col0 + wn * 64 + nt * 16 + l15;
        const float bb = bias[gn];
        const int hh = gn >> 6, dd = gn & 63;
#pragma unroll
        for (int mt = 0; mt < 4; mt++) {
#pragma unroll
            for (int r = 0; r < 4; r++) {
                const int tok = row0 + wm * 64 + mt * 16 + quad * 4 + r;
                const int b = tok >> 10, s = tok & 1023;
                float vv = acc[mt][nt][r] + bb;
                size_t addr;
                if (mode == 2) {
                    addr = ((size_t)((b * NHEAD + hh) * HDIM + dd)) * SEQLEN + s;
                } else {
                    if (mode == 0) vv *= 0.125f;  // 1/sqrt(Dk), exact pow2
                    addr = ((size_t)((b * NHEAD + hh) * SEQLEN + s)) * HDIM + dd;
                }
                out[addr] = (bf16_t)vv;
            }
        }
    }
}

// ---------------- output projection GEMM, 64x128 tile, swizzled row-major LDS ----------------
__global__ __launch_bounds__(256) void gemm_o(
    const bf16_t* __restrict__ Xa, const bf16_t* __restrict__ Wt,
    const float* __restrict__ bias, float* __restrict__ out)
{
    __shared__ __align__(16) bf16_t lA[64 * 32];     // 4KB, 4 words/row
    __shared__ __align__(16) bf16_t lB[128 * 32];    // 8KB, 4 words/row

    const int wave = threadIdx.x >> 6, lane = threadIdx.x & 63;
    const int quad = lane >> 4, l15 = lane & 15;
    const int wm = wave & 1, wn = wave >> 1;
    const int row0 = blockIdx.x * 64, col0 = blockIdx.y * 128;
    const int brl = lane >> 2, bc = lane & 3;

    const floatx4 zero = {0.f, 0.f, 0.f, 0.f};
    floatx4 acc[2][4];
#pragma unroll
    for (int mt = 0; mt < 2; mt++)
#pragma unroll
        for (int nt = 0; nt < 4; nt++) acc[mt][nt] = zero;

    for (int k0 = 0; k0 < DMODEL; k0 += 32) {
        // A: 4 segs (1/wave): rows wave*16+brl
        {
            const int r = wave * 16 + brl;
            const int q = bc ^ ((r >> 1) & 3);
            gload16(Xa + (size_t)(row0 + r) * DMODEL + k0 + q * 8, lA + wave * 512);
        }
        // B: 8 segs (2/wave)
#pragma unroll
        for (int j = 0; j < 2; j++) {
            const int s = wave * 2 + j;
            const int r = s * 16 + brl;
            const int q = bc ^ ((r >> 1) & 3);
            gload16(Wt + (size_t)(col0 + r) * DMODEL + k0 + q * 8, lB + s * 512);
        }
        __syncthreads();
        bf16x8 aF[2], bF[4];
#pragma unroll
        for (int t = 0; t < 2; t++) {
            const int ra = wm * 32 + t * 16 + l15;
            const int wa = ra * 4 + (quad ^ ((ra >> 1) & 3));
            aF[t] = *(const bf16x8*)(lA + wa * 8);
        }
#pragma unroll
        for (int t = 0; t < 4; t++) {
            const int rb = wn * 64 + t * 16 + l15;
            const int wb = rb * 4 + (quad ^ ((rb >> 1) & 3));
            bF[t] = *(const bf16x8*)(lB + wb * 8);
        }
#pragma unroll
        for (int mt = 0; mt < 2; mt++)
#pragma unroll
            for (int nt = 0; nt < 4; nt++)
                acc[mt][nt] = MFMA_BF16(aF[mt], bF[nt], acc[mt][nt]);
        __syncthreads();
    }

#pragma unroll
    for (int nt = 0; nt < 4; nt++) {
        const int gn = col0 + wn * 64 + nt * 16 + l15;
        const float bb = bias[gn];
#pragma unroll
        for (int mt = 0; mt < 2; mt++) {
#pragma unroll
            for (int r = 0; r < 4; r++) {
                const int tok = row0 + wm * 32 + mt * 16 + quad * 4 + r;
                out[(size_t)tok * DMODEL + gn] = acc[mt][nt][r] + bb;
            }
        }
    }
}

// ---------------- causal flash attention: dual-stream, pair-balanced, no LDS ----------------
__global__ __launch_bounds__(256) void attn(
    const bf16_t* __restrict__ Qh, const bf16_t* __restrict__ Kh,
    const bf16_t* __restrict__ Vt, bf16_t* __restrict__ X)
{
    const int wave = threadIdx.x >> 6, lane = threadIdx.x & 63;
    const int quad = lane >> 4, l15 = lane & 15;
    const int L = blockIdx.x;                          // [0,512)
    const int bh = (L & 7) * 8 + ((L >> 3) & 7);       // same 8 heads stay on one XCD
    const int pb = L >> 6;                             // [0,8)
    const int t  = pb * 4 + wave;                      // pair index [0,32)
    const int b = bh >> 4, h = bh & 15;

    const int qbaseA = 16 * t, qbaseB = 1008 - 16 * t;
    const int qrowA = qbaseA + l15, qrowB = qbaseB + l15;
    const int nkA = t / 2 + 1, nkB = 32 - t / 2;

    const bf16_t* Qp = Qh + (size_t)bh * SEQLEN * HDIM;
    const bf16_t* Kp = Kh + (size_t)bh * SEQLEN * HDIM;
    const bf16_t* Vp = Vt + (size_t)bh * HDIM * SEQLEN;

    bf16x8 bQA[2], bQB[2];
#pragma unroll
    for (int c = 0; c < 2; c++) {
        bQA[c] = *(const bf16x8*)(Qp + (size_t)qrowA * HDIM + c * 32 + quad * 8);
        bQB[c] = *(const bf16x8*)(Qp + (size_t)qrowB * HDIM + c * 32 + quad * 8);
    }

    const floatx4 zero = {0.f, 0.f, 0.f, 0.f};
    float mA = -INFINITY, lA_ = 0.f, mB = -INFINITY, lB_ = 0.f;
    floatx4 oA[4], oB[4];
#pragma unroll
    for (int dt = 0; dt < 4; dt++) { oA[dt] = zero; oB[dt] = zero; }

    const int srcA = ((quad & 1) ? 32 : 0) + l15;
    const int srcB = srcA + 16;
    const bool hiP = (quad >= 2);

    for (int kc = 0; kc < nkB; kc++) {
        const int kb = kc * 32;
        bf16x8 aK0[2], aK1[2], aV[4];
#pragma unroll
        for (int c = 0; c < 2; c++) {
            aK0[c] = *(const bf16x8*)(Kp + (size_t)(kb + l15) * HDIM + c * 32 + quad * 8);
            aK1[c] = *(const bf16x8*)(Kp + (size_t)(kb + 16 + l15) * HDIM + c * 32 + quad * 8);
        }
#pragma unroll
        for (int dt = 0; dt < 4; dt++)
            aV[dt] = *(const bf16x8*)(Vp + (size_t)(dt * 16 + l15) * SEQLEN + kb + quad * 8);

        const bool doA = (kc < nkA);

        floatx4 S0B = zero, S1B = zero, S0A = zero, S1A = zero;
#pragma unroll
        for (int c = 0; c < 2; c++) {
            S0B = MFMA_BF16(aK0[c], bQB[c], S0B);
            S1B = MFMA_BF16(aK1[c], bQB[c], S1B);
        }
        if (doA) {
#pragma unroll
            for (int c = 0; c < 2; c++) {
                S0A = MFMA_BF16(aK0[c], bQA[c], S0A);
                S1A = MFMA_BF16(aK1[c], bQA[c], S1A);
            }
        }

        {   // stream B
            float s0[4], s1[4], mx = -1e30f;
#pragma unroll
            for (int r = 0; r < 4; r++) {
                const int key0 = kb + quad * 4 + r;
                s0[r] = (key0 <= qrowB)      ? S0B[r] : -1e30f;
                s1[r] = (key0 + 16 <= qrowB) ? S1B[r] : -1e30f;
                mx = fmaxf(mx, fmaxf(s0[r], s1[r]));
            }
            mx = fmaxf(mx, __shfl_xor(mx, 16));
            mx = fmaxf(mx, __shfl_xor(mx, 32));
            const float mn = fmaxf(mB, mx);
            const float alpha = __expf(mB - mn);
            mB = mn;
            float ps = 0.f;
            union { bf16_t hh2[8]; u32 u[4]; } pk;
#pragma unroll
            for (int r = 0; r < 4; r++) {
                float e0 = __expf(s0[r] - mn), e1 = __expf(s1[r] - mn);
                ps += e0 + e1;
                pk.hh2[r] = (bf16_t)e0; pk.hh2[4 + r] = (bf16_t)e1;
            }
            ps += __shfl_xor(ps, 16);
            ps += __shfl_xor(ps, 32);
            lB_ = lB_ * alpha + ps;
#pragma unroll
            for (int dt = 0; dt < 4; dt++)
#pragma unroll
                for (int r = 0; r < 4; r++) oB[dt][r] *= alpha;
            u32 a0 = __shfl(pk.u[0], srcA), a1 = __shfl(pk.u[1], srcA);
            u32 a2 = __shfl(pk.u[0], srcB), a3 = __shfl(pk.u[1], srcB);
            u32 b0 = __shfl(pk.u[2], srcA), b1 = __shfl(pk.u[3], srcA);
            u32 b2 = __shfl(pk.u[2], srcB), b3 = __shfl(pk.u[3], srcB);
            union { u32 u[4]; bf16x8 v; } bP;
            bP.u[0] = hiP ? b0 : a0; bP.u[1] = hiP ? b1 : a1;
            bP.u[2] = hiP ? b2 : a2; bP.u[3] = hiP ? b3 : a3;
#pragma unroll
            for (int dt = 0; dt < 4; dt++) oB[dt] = MFMA_BF16(aV[dt], bP.v, oB[dt]);
        }

        if (doA) {  // stream A
            float s0[4], s1[4], mx = -1e30f;
#pragma unroll
            for (int r = 0; r < 4; r++) {
                const int key0 = kb + quad * 4 + r;
                s0[r] = (key0 <= qrowA)      ? S0A[r] : -1e30f;
                s1[r] = (key0 + 16 <= qrowA) ? S1A[r] : -1e30f;
                mx = fmaxf(mx, fmaxf(s0[r], s1[r]));
            }
            mx = fmaxf(mx, __shfl_xor(mx, 16));
            mx = fmaxf(mx, __shfl_xor(mx, 32));
            const float mn = fmaxf(mA, mx);
            const float alpha = __expf(mA - mn);
            mA = mn;
            float ps = 0.f;
            union { bf16_t hh2[8]; u32 u[4]; } pk;
#pragma unroll
            for (int r = 0; r < 4; r++) {
                float e0 = __expf(s0[r] - mn), e1 = __expf(s1[r] - mn);
                ps += e0 + e1;
                pk.hh2[r] = (bf16_t)e0; pk.hh2[4 + r] = (bf16_t)e1;
            }
            ps += __shfl_xor(ps, 16);
            ps += __shfl_xor(ps, 32);
            lA_ = lA_ * alpha + ps;
#pragma unroll
            for (int dt = 0; dt < 4; dt++)
#pragma unroll
                for (int r = 0; r < 4; r++) oA[dt][r] *= alpha;
            u32 a0 = __shfl(pk.u[0], srcA), a1 = __shfl(pk.u[1], srcA);
            u32 a2 = __shfl(pk.u[0], srcB), a3 = __shfl(pk.u[1], srcB);
            u32 b0 = __shfl(pk.u[2], srcA), b1 = __shfl(pk.u[3], srcA);
            u32 b2 = __shfl(pk.u[2], srcB), b3 = __shfl(pk.u[3], srcB);
            union { u32 u[4]; bf16x8 v; } bP;
            bP.u[0] = hiP ? b0 : a0; bP.u[1] = hiP ? b1 : a1;
            bP.u[2] = hiP ? b2 : a2; bP.u[3] = hiP ? b3 : a3;
#pragma unroll
            for (int dt = 0; dt < 4; dt++) oA[dt] = MFMA_BF16(aV[dt], bP.v, oA[dt]);
        }
    }

    const float invA = 1.f / lA_, invB = 1.f / lB_;
#pragma unroll
    for (int dt = 0; dt < 4; dt++) {
        bf16x4 va, vb;
#pragma unroll
        for (int r = 0; r < 4; r++) {
            va[r] = (bf16_t)(oA[dt][r] * invA);
            vb[r] = (bf16_t)(oB[dt][r] * invB);
        }
        const size_t cofs = (size_t)h * HDIM + dt * 16 + quad * 4;
        *(bf16x4*)(&X[((size_t)(b * SEQLEN + qrowA)) * DMODEL + cofs]) = va;
        *(bf16x4*)(&X[((size_t)(b * SEQLEN + qrowB)) * DMODEL + cofs]) = vb;
    }
}

extern "C" void kernel_launch(void* const* d_in, const int* in_sizes, int n_in,
                              void* d_out, int out_size, void* d_ws, size_t ws_size,
                              hipStream_t stream)
{
    const float* q  = (const float*)d_in[0];
    const float* k  = (const float*)d_in[1];
    const float* v  = (const float*)d_in[2];
    // d_in[3] = causal mask (deterministic tril) — applied analytically
    const float* Wq = (const float*)d_in[4];
    const float* bq = (const float*)d_in[5];
    const float* Wk = (const float*)d_in[6];
    const float* bk = (const float*)d_in[7];
    const float* Wv = (const float*)d_in[8];
    const float* bv = (const float*)d_in[9];
    const float* Wo = (const float*)d_in[10];
    const float* bo = (const float*)d_in[11];
    float* out = (float*)d_out;

    char* ws = (char*)d_ws;
    const size_t MB = 1ull << 20;
    bf16_t* Wt = (bf16_t*)ws;                              // [0,8) MB: 4 transposed bf16 weights
    bf16_t* Qh = (bf16_t*)(ws + 8 * MB);                   // [8,16)
    bf16_t* Kh = (bf16_t*)(ws + 16 * MB);                  // [16,24)
    bf16_t* Vt = (bf16_t*)(ws + 24 * MB);                  // [24,32)
    bf16_t* Xa = (bf16_t*)(ws + 32 * MB);                  // [32,40) attn output bf16

    transpose_w<<<dim3(32, 32, 4), dim3(32, 8), 0, stream>>>(Wq, Wk, Wv, Wo, Wt);
    gemm_qkv<<<dim3(32, 8, 3), dim3(256), 0, stream>>>(
        q, k, v, Wt, bq, bk, bv, Qh, Kh, Vt);
    attn<<<dim3(512), dim3(256), 0, stream>>>(Qh, Kh, Vt, Xa);
    gemm_o<<<dim3(64, 8), dim3(256), 0, stream>>>(
        Xa, Wt + 3 * (size_t)DMODEL * DMODEL, bo, out);
}

// Round 8
// 237.756 us; speedup vs baseline: 1.2987x; 1.1454x over previous
//
#include <hip/hip_runtime.h>
#include <math.h>

typedef __bf16 bf16_t;
typedef bf16_t bf16x8 __attribute__((ext_vector_type(8)));
typedef bf16_t bf16x4 __attribute__((ext_vector_type(4)));
typedef float  floatx4 __attribute__((ext_vector_type(4)));
typedef unsigned int u32;

#define MFMA_BF16(a, b, c) __builtin_amdgcn_mfma_f32_16x16x32_bf16((a), (b), (c), 0, 0, 0)

static constexpr int DMODEL = 1024;
static constexpr int NHEAD  = 16;
static constexpr int HDIM   = 64;
static constexpr int NBATCH = 4;
static constexpr int SEQLEN = 1024;
static constexpr int NTOK   = NBATCH * SEQLEN;  // 4096

typedef __attribute__((address_space(3))) void       as3_void;
typedef __attribute__((address_space(1))) const void as1_cvoid;

// async global->LDS, 16B/lane; LDS dest = wave-uniform base + lane*16
__device__ __forceinline__ void gload16(const void* g, void* l) {
    __builtin_amdgcn_global_load_lds((as1_cvoid*)g, (as3_void*)l, 16, 0, 0);
}

// load 8 consecutive fp32, round to bf16x8
__device__ __forceinline__ bf16x8 load_cvt8(const float* __restrict__ p) {
    floatx4 a = *(const floatx4*)p;
    floatx4 b = *(const floatx4*)(p + 4);
    bf16x8 r;
    r[0] = (bf16_t)a[0]; r[1] = (bf16_t)a[1]; r[2] = (bf16_t)a[2]; r[3] = (bf16_t)a[3];
    r[4] = (bf16_t)b[0]; r[5] = (bf16_t)b[1]; r[6] = (bf16_t)b[2]; r[7] = (bf16_t)b[3];
    return r;
}

// ---------------- fp32 -> bf16 convert ----------------
__global__ __launch_bounds__(256) void cvt3_bf16(
    const float* __restrict__ s0, const float* __restrict__ s1, const float* __restrict__ s2,
    bf16_t* __restrict__ dst, size_t dstride)
{
    const float* src = (blockIdx.y == 0) ? s0 : (blockIdx.y == 1) ? s1 : s2;
    size_t i = ((size_t)blockIdx.x * 256 + threadIdx.x) * 8;
    *(bf16x8*)(dst + blockIdx.y * dstride + i) = load_cvt8(src + i);
}
__global__ __launch_bounds__(256) void cvt_bf16(
    const float* __restrict__ src, bf16_t* __restrict__ dst)
{
    size_t i = ((size_t)blockIdx.x * 256 + threadIdx.x) * 8;
    *(bf16x8*)(dst + i) = load_cvt8(src + i);
}

// ---------------- weight transpose+convert: Wt[n][k] = bf16(W[k][n]), 4 mats ----------------
__global__ __launch_bounds__(256) void transpose_w(
    const float* __restrict__ W0, const float* __restrict__ W1,
    const float* __restrict__ W2, const float* __restrict__ W3,
    bf16_t* __restrict__ out)
{
    __shared__ float tile[32][33];
    const float* W = (blockIdx.z == 0) ? W0 : (blockIdx.z == 1) ? W1
                   : (blockIdx.z == 2) ? W2 : W3;
    bf16_t* O = out + (size_t)blockIdx.z * DMODEL * DMODEL;
    int tx = threadIdx.x, ty = threadIdx.y;           // 32 x 8
    int r0 = blockIdx.x * 32, c0 = blockIdx.y * 32;
#pragma unroll
    for (int i = 0; i < 32; i += 8)
        tile[ty + i][tx] = W[(size_t)(r0 + ty + i) * DMODEL + c0 + tx];
    __syncthreads();
#pragma unroll
    for (int i = 0; i < 32; i += 8)
        O[(size_t)(c0 + ty + i) * DMODEL + r0 + tx] = (bf16_t)tile[tx][ty + i];
}

// ---------------- QKV projection GEMM, 128x128 tile, BK=32, dbuf single-barrier ----------------
// Prefetch for iter it+1 is issued right AFTER barrier(it); compute(it) overlaps the DMA;
// barrier(it+1)'s implicit vmcnt(0) drains it only after a full compute phase.
__global__ __launch_bounds__(256) void gemm_qkv(
    const bf16_t* __restrict__ Xb, size_t astride, int mode0,
    const bf16_t* __restrict__ Wt,
    const float* __restrict__ bq, const float* __restrict__ bk, const float* __restrict__ bv,
    bf16_t* __restrict__ Qh, bf16_t* __restrict__ Kh, bf16_t* __restrict__ Vt)
{
    const int mode = mode0 + blockIdx.z;
    const bf16_t* A = Xb + astride * (size_t)blockIdx.z;
    const bf16_t* B = Wt + (size_t)mode * DMODEL * DMODEL;
    const float* bias = (mode == 0) ? bq : (mode == 1) ? bk : bv;
    bf16_t* out       = (mode == 0) ? Qh : (mode == 1) ? Kh : Vt;

    __shared__ __align__(16) bf16_t lA[2][128 * 32];
    __shared__ __align__(16) bf16_t lB[2][128 * 32];

    const int wave = threadIdx.x >> 6, lane = threadIdx.x & 63;
    const int quad = lane >> 4, l15 = lane & 15;
    const int wm = wave >> 1, wn = wave & 1;
    const int row0 = blockIdx.x * 128, col0 = blockIdx.y * 128;
    const int srow = lane >> 2, scol = (lane & 3) * 8;   // 16 rows/seg, 64B/row

    const floatx4 zero = {0.f, 0.f, 0.f, 0.f};
    floatx4 acc[4][4];
#pragma unroll
    for (int mt = 0; mt < 4; mt++)
#pragma unroll
        for (int nt = 0; nt < 4; nt++) acc[mt][nt] = zero;

    // prologue: stage k0=0 into buf 0
#pragma unroll
    for (int j = 0; j < 2; j++) {
        const int seg = j * 4 + wave;
        gload16(A + (size_t)(row0 + seg * 16 + srow) * DMODEL + scol, lA[0] + seg * 512);
        gload16(B + (size_t)(col0 + seg * 16 + srow) * DMODEL + scol, lB[0] + seg * 512);
    }

    for (int it = 0; it < 32; it++) {
        __syncthreads();                       // drains stage(it); all waves done reading buf it^1
        const int cur = it & 1;
        if (it + 1 < 32) {
            const int k1 = (it + 1) * 32;
            const int nb = cur ^ 1;
#pragma unroll
            for (int j = 0; j < 2; j++) {
                const int seg = j * 4 + wave;
                gload16(A + (size_t)(row0 + seg * 16 + srow) * DMODEL + k1 + scol, lA[nb] + seg * 512);
                gload16(B + (size_t)(col0 + seg * 16 + srow) * DMODEL + k1 + scol, lB[nb] + seg * 512);
            }
        }
        bf16x8 aF[4], bF[4];
#pragma unroll
        for (int t = 0; t < 4; t++) {
            aF[t] = *(const bf16x8*)(lA[cur] + (wm * 64 + t * 16 + l15) * 32 + quad * 8);
            bF[t] = *(const bf16x8*)(lB[cur] + (wn * 64 + t * 16 + l15) * 32 + quad * 8);
        }
#pragma unroll
        for (int mt = 0; mt < 4; mt++)
#pragma unroll
            for (int nt = 0; nt < 4; nt++)
                acc[mt][nt] = MFMA_BF16(aF[mt], bF[nt], acc[mt][nt]);
    }

#pragma unroll
    for (int nt = 0; nt < 4; nt++) {
        const int gn = col0 + wn * 64 + nt * 16 + l15;
        const float bb = bias[gn];
        const int hh = gn >> 6, dd = gn & 63;
#pragma unroll
        for (int mt = 0; mt < 4; mt++) {
#pragma unroll
            for (int r = 0; r < 4; r++) {
                const int tok = row0 + wm * 64 + mt * 16 + quad * 4 + r;
                const int b = tok >> 10, s = tok & 1023;
                float vv = acc[mt][nt][r] + bb;
                size_t addr;
                if (mode == 2) {
                    addr = ((size_t)((b * NHEAD + hh) * HDIM + dd)) * SEQLEN + s;
                } else {
                    if (mode == 0) vv *= 0.125f;  // 1/sqrt(Dk), exact pow2
                    addr = ((size_t)((b * NHEAD + hh) * SEQLEN + s)) * HDIM + dd;
                }
                out[addr] = (bf16_t)vv;
            }
        }
    }
}

// ---------------- output projection GEMM, 64x128 tile, dbuf single-barrier ----------------
__global__ __launch_bounds__(256) void gemm_o(
    const bf16_t* __restrict__ Xa, const bf16_t* __restrict__ Wt,
    const float* __restrict__ bias, float* __restrict__ out)
{
    __shared__ __align__(16) bf16_t lA[2][64 * 32];
    __shared__ __align__(16) bf16_t lB[2][128 * 32];

    const int wave = threadIdx.x >> 6, lane = threadIdx.x & 63;
    const int quad = lane >> 4, l15 = lane & 15;
    const int wm = wave & 1, wn = wave >> 1;
    const int row0 = blockIdx.x * 64, col0 = blockIdx.y * 128;
    const int srow = lane >> 2, scol = (lane & 3) * 8;

    const floatx4 zero = {0.f, 0.f, 0.f, 0.f};
    floatx4 acc[2][4];
#pragma unroll
    for (int mt = 0; mt < 2; mt++)
#pragma unroll
        for (int nt = 0; nt < 4; nt++) acc[mt][nt] = zero;

    // prologue
    gload16(Xa + (size_t)(row0 + wave * 16 + srow) * DMODEL + scol, lA[0] + wave * 512);
#pragma unroll
    for (int j = 0; j < 2; j++) {
        const int seg = wave * 2 + j;
        gload16(Wt + (size_t)(col0 + seg * 16 + srow) * DMODEL + scol, lB[0] + seg * 512);
    }

    for (int it = 0; it < 32; it++) {
        __syncthreads();
        const int cur = it & 1;
        if (it + 1 < 32) {
            const int k1 = (it + 1) * 32;
            const int nb = cur ^ 1;
            gload16(Xa + (size_t)(row0 + wave * 16 + srow) * DMODEL + k1 + scol, lA[nb] + wave * 512);
#pragma unroll
            for (int j = 0; j < 2; j++) {
                const int seg = wave * 2 + j;
                gload16(Wt + (size_t)(col0 + seg * 16 + srow) * DMODEL + k1 + scol, lB[nb] + seg * 512);
            }
        }
        bf16x8 aF[2], bF[4];
#pragma unroll
        for (int t = 0; t < 2; t++)
            aF[t] = *(const bf16x8*)(lA[cur] + (wm * 32 + t * 16 + l15) * 32 + quad * 8);
#pragma unroll
        for (int t = 0; t < 4; t++)
            bF[t] = *(const bf16x8*)(lB[cur] + (wn * 64 + t * 16 + l15) * 32 + quad * 8);
#pragma unroll
        for (int mt = 0; mt < 2; mt++)
#pragma unroll
            for (int nt = 0; nt < 4; nt++)
                acc[mt][nt] = MFMA_BF16(aF[mt], bF[nt], acc[mt][nt]);
    }

#pragma unroll
    for (int nt = 0; nt < 4; nt++) {
        const int gn = col0 + wn * 64 + nt * 16 + l15;
        const float bb = bias[gn];
#pragma unroll
        for (int mt = 0; mt < 2; mt++) {
#pragma unroll
            for (int r = 0; r < 4; r++) {
                const int tok = row0 + wm * 32 + mt * 16 + quad * 4 + r;
                out[(size_t)tok * DMODEL + gn] = acc[mt][nt][r] + bb;
            }
        }
    }
}

// ---------------- causal flash attention: dual-stream, pair-balanced, no LDS ----------------
__global__ __launch_bounds__(256) void attn(
    const bf16_t* __restrict__ Qh, const bf16_t* __restrict__ Kh,
    const bf16_t* __restrict__ Vt, bf16_t* __restrict__ X)
{
    const int wave = threadIdx.x >> 6, lane = threadIdx.x & 63;
    const int quad = lane >> 4, l15 = lane & 15;
    const int L = blockIdx.x;                          // [0,512)
    const int bh = (L & 7) * 8 + ((L >> 3) & 7);       // same 8 heads stay on one XCD
    const int pb = L >> 6;                             // [0,8)
    const int t  = pb * 4 + wave;                      // pair index [0,32)
    const int b = bh >> 4, h = bh & 15;

    const int qbaseA = 16 * t, qbaseB = 1008 - 16 * t;
    const int qrowA = qbaseA + l15, qrowB = qbaseB + l15;
    const int nkA = t / 2 + 1, nkB = 32 - t / 2;

    const bf16_t* Qp = Qh + (size_t)bh * SEQLEN * HDIM;
    const bf16_t* Kp = Kh + (size_t)bh * SEQLEN * HDIM;
    const bf16_t* Vp = Vt + (size_t)bh * HDIM * SEQLEN;

    bf16x8 bQA[2], bQB[2];
#pragma unroll
    for (int c = 0; c < 2; c++) {
        bQA[c] = *(const bf16x8*)(Qp + (size_t)qrowA * HDIM + c * 32 + quad * 8);
        bQB[c] = *(const bf16x8*)(Qp + (size_t)qrowB * HDIM + c * 32 + quad * 8);
    }

    const floatx4 zero = {0.f, 0.f, 0.f, 0.f};
    float mA = -INFINITY, lA_ = 0.f, mB = -INFINITY, lB_ = 0.f;
    floatx4 oA[4], oB[4];
#pragma unroll
    for (int dt = 0; dt < 4; dt++) { oA[dt] = zero; oB[dt] = zero; }

    const int srcA = ((quad & 1) ? 32 : 0) + l15;
    const int srcB = srcA + 16;
    const bool hiP = (quad >= 2);

    for (int kc = 0; kc < nkB; kc++) {
        const int kb = kc * 32;
        bf16x8 aK0[2], aK1[2], aV[4];
#pragma unroll
        for (int c = 0; c < 2; c++) {
            aK0[c] = *(const bf16x8*)(Kp + (size_t)(kb + l15) * HDIM + c * 32 + quad * 8);
            aK1[c] = *(const bf16x8*)(Kp + (size_t)(kb + 16 + l15) * HDIM + c * 32 + quad * 8);
        }
#pragma unroll
        for (int dt = 0; dt < 4; dt++)
            aV[dt] = *(const bf16x8*)(Vp + (size_t)(dt * 16 + l15) * SEQLEN + kb + quad * 8);

        const bool doA = (kc < nkA);

        floatx4 S0B = zero, S1B = zero, S0A = zero, S1A = zero;
#pragma unroll
        for (int c = 0; c < 2; c++) {
            S0B = MFMA_BF16(aK0[c], bQB[c], S0B);
            S1B = MFMA_BF16(aK1[c], bQB[c], S1B);
        }
        if (doA) {
#pragma unroll
            for (int c = 0; c < 2; c++) {
                S0A = MFMA_BF16(aK0[c], bQA[c], S0A);
                S1A = MFMA_BF16(aK1[c], bQA[c], S1A);
            }
        }

        {   // stream B
            float s0[4], s1[4], mx = -1e30f;
#pragma unroll
            for (int r = 0; r < 4; r++) {
                const int key0 = kb + quad * 4 + r;
                s0[r] = (key0 <= qrowB)      ? S0B[r] : -1e30f;
                s1[r] = (key0 + 16 <= qrowB) ? S1B[r] : -1e30f;
                mx = fmaxf(mx, fmaxf(s0[r], s1[r]));
            }
            mx = fmaxf(mx, __shfl_xor(mx, 16));
            mx = fmaxf(mx, __shfl_xor(mx, 32));
            const float mn = fmaxf(mB, mx);
            const float alpha = __expf(mB - mn);
            mB = mn;
            float ps = 0.f;
            union { bf16_t hh2[8]; u32 u[4]; } pk;
#pragma unroll
            for (int r = 0; r < 4; r++) {
                float e0 = __expf(s0[r] - mn), e1 = __expf(s1[r] - mn);
                ps += e0 + e1;
                pk.hh2[r] = (bf16_t)e0; pk.hh2[4 + r] = (bf16_t)e1;
            }
            ps += __shfl_xor(ps, 16);
            ps += __shfl_xor(ps, 32);
            lB_ = lB_ * alpha + ps;
#pragma unroll
            for (int dt = 0; dt < 4; dt++)
#pragma unroll
                for (int r = 0; r < 4; r++) oB[dt][r] *= alpha;
            u32 a0 = __shfl(pk.u[0], srcA), a1 = __shfl(pk.u[1], srcA);
            u32 a2 = __shfl(pk.u[0], srcB), a3 = __shfl(pk.u[1], srcB);
            u32 b0 = __shfl(pk.u[2], srcA), b1 = __shfl(pk.u[3], srcA);
            u32 b2 = __shfl(pk.u[2], srcB), b3 = __shfl(pk.u[3], srcB);
            union { u32 u[4]; bf16x8 v; } bP;
            bP.u[0] = hiP ? b0 : a0; bP.u[1] = hiP ? b1 : a1;
            bP.u[2] = hiP ? b2 : a2; bP.u[3] = hiP ? b3 : a3;
#pragma unroll
            for (int dt = 0; dt < 4; dt++) oB[dt] = MFMA_BF16(aV[dt], bP.v, oB[dt]);
        }

        if (doA) {  // stream A
            float s0[4], s1[4], mx = -1e30f;
#pragma unroll
            for (int r = 0; r < 4; r++) {
                const int key0 = kb + quad * 4 + r;
                s0[r] = (key0 <= qrowA)      ? S0A[r] : -1e30f;
                s1[r] = (key0 + 16 <= qrowA) ? S1A[r] : -1e30f;
                mx = fmaxf(mx, fmaxf(s0[r], s1[r]));
            }
            mx = fmaxf(mx, __shfl_xor(mx, 16));
            mx = fmaxf(mx, __shfl_xor(mx, 32));
            const float mn = fmaxf(mA, mx);
            const float alpha = __expf(mA - mn);
            mA = mn;
            float ps = 0.f;
            union { bf16_t hh2[8]; u32 u[4]; } pk;
#pragma unroll
            for (int r = 0; r < 4; r++) {
                float e0 = __expf(s0[r] - mn), e1 = __expf(s1[r] - mn);
                ps += e0 + e1;
                pk.hh2[r] = (bf16_t)e0; pk.hh2[4 + r] = (bf16_t)e1;
            }
            ps += __shfl_xor(ps, 16);
            ps += __shfl_xor(ps, 32);
            lA_ = lA_ * alpha + ps;
#pragma unroll
            for (int dt = 0; dt < 4; dt++)
#pragma unroll
                for (int r = 0; r < 4; r++) oA[dt][r] *= alpha;
            u32 a0 = __shfl(pk.u[0], srcA), a1 = __shfl(pk.u[1], srcA);
            u32 a2 = __shfl(pk.u[0], srcB), a3 = __shfl(pk.u[1], srcB);
            u32 b0 = __shfl(pk.u[2], srcA), b1 = __shfl(pk.u[3], srcA);
            u32 b2 = __shfl(pk.u[2], srcB), b3 = __shfl(pk.u[3], srcB);
            union { u32 u[4]; bf16x8 v; } bP;
            bP.u[0] = hiP ? b0 : a0; bP.u[1] = hiP ? b1 : a1;
            bP.u[2] = hiP ? b2 : a2; bP.u[3] = hiP ? b3 : a3;
#pragma unroll
            for (int dt = 0; dt < 4; dt++) oA[dt] = MFMA_BF16(aV[dt], bP.v, oA[dt]);
        }
    }

    const float invA = 1.f / lA_, invB = 1.f / lB_;
#pragma unroll
    for (int dt = 0; dt < 4; dt++) {
        bf16x4 va, vb;
#pragma unroll
        for (int r = 0; r < 4; r++) {
            va[r] = (bf16_t)(oA[dt][r] * invA);
            vb[r] = (bf16_t)(oB[dt][r] * invB);
        }
        const size_t cofs = (size_t)h * HDIM + dt * 16 + quad * 4;
        *(bf16x4*)(&X[((size_t)(b * SEQLEN + qrowA)) * DMODEL + cofs]) = va;
        *(bf16x4*)(&X[((size_t)(b * SEQLEN + qrowB)) * DMODEL + cofs]) = vb;
    }
}

extern "C" void kernel_launch(void* const* d_in, const int* in_sizes, int n_in,
                              void* d_out, int out_size, void* d_ws, size_t ws_size,
                              hipStream_t stream)
{
    const float* qkv_in[3] = {(const float*)d_in[0], (const float*)d_in[1], (const float*)d_in[2]};
    // d_in[3] = causal mask (deterministic tril) — applied analytically
    const float* Wq = (const float*)d_in[4];
    const float* bq = (const float*)d_in[5];
    const float* Wk = (const float*)d_in[6];
    const float* bk = (const float*)d_in[7];
    const float* Wv = (const float*)d_in[8];
    const float* bv = (const float*)d_in[9];
    const float* Wo = (const float*)d_in[10];
    const float* bo = (const float*)d_in[11];
    float* out = (float*)d_out;

    char* ws = (char*)d_ws;
    const size_t MB = 1ull << 20;
    const size_t NELEM = (size_t)NTOK * DMODEL;            // 4M elements / 8 MB bf16
    bf16_t* Wt = (bf16_t*)ws;                              // [0,8) MB: 4 transposed bf16 weights
    bf16_t* Qh = (bf16_t*)(ws + 8 * MB);                   // [8,16)
    bf16_t* Kh = (bf16_t*)(ws + 16 * MB);                  // [16,24)
    bf16_t* Vt = (bf16_t*)(ws + 24 * MB);                  // [24,32)
    bf16_t* Xr = (bf16_t*)(ws + 32 * MB);                  // [32,...) bf16 staging; Xa overlays

    transpose_w<<<dim3(32, 32, 4), dim3(32, 8), 0, stream>>>(Wq, Wk, Wv, Wo, Wt);

    if (ws_size >= 56 * MB) {
        cvt3_bf16<<<dim3(2048, 3), dim3(256), 0, stream>>>(
            qkv_in[0], qkv_in[1], qkv_in[2], Xr, NELEM);
        gemm_qkv<<<dim3(32, 8, 3), dim3(256), 0, stream>>>(
            Xr, NELEM, 0, Wt, bq, bk, bv, Qh, Kh, Vt);
    } else {
        for (int m = 0; m < 3; m++) {
            cvt_bf16<<<dim3(2048), dim3(256), 0, stream>>>(qkv_in[m], Xr);
            gemm_qkv<<<dim3(32, 8, 1), dim3(256), 0, stream>>>(
                Xr, 0, m, Wt, bq, bk, bv, Qh, Kh, Vt);
        }
    }

    // attn writes Xa over Xr[0..8MB) (q's bf16 copy, dead after gemm_qkv)
    bf16_t* Xa = Xr;
    attn<<<dim3(512), dim3(256), 0, stream>>>(Qh, Kh, Vt, Xa);
    gemm_o<<<dim3(64, 8), dim3(256), 0, stream>>>(
        Xa, Wt + 3 * (size_t)DMODEL * DMODEL, bo, out);
}